// Round 3
// baseline (431.766 us; speedup 1.0000x reference)
//
#include <hip/hip_runtime.h>

// Problem constants (from the reference):
//   B=8, H=32, W=32, T=4, BS=3, D=768, SMAX=2, P=2560
// Output [B,H,W,T,BS,D] float32. Every (y,x,t) cell is covered by exactly
// one patch, so a direct scatter writes every output element exactly once.
//
// R3: same as R2 but with clang ext_vector_type(4) float ("f4") instead of
// HIP_vector_type float4, because __builtin_nontemporal_store only accepts
// scalar/native-vector pointee types.
//   - 4 patches per 192-thread block; 12 source f4 loaded up front
//     (contiguous 36KB span -> 12 outstanding dwordx4/thread)
//   - nontemporal stores (write-once stream; keep L3-warm input resident)
//   - 2D grid (blockIdx.y = b) kills the bp/P division

typedef float f4 __attribute__((ext_vector_type(4)));

constexpr int H_ = 32;
constexpr int W_ = 32;
constexpr int T_ = 4;
constexpr int BS_ = 3;
constexpr int D_ = 768;
constexpr int CD  = BS_ * D_;   // 2304 floats per cell
constexpr int CD4 = CD / 4;     // 576 f4 per cell
constexpr int BLOCK = 192;      // 3 waves; 576 = 3*192
constexpr int PPB = 4;          // patches per block

__global__ __launch_bounds__(BLOCK) void apt_scatter_kernel(
    const f4* __restrict__ tok,   // [B*P, CD4]
    const int4* __restrict__ pos, // [B*P] (y, x, size, t)
    f4* __restrict__ out,         // [B,H,W,T, CD4]
    int P)
{
    const int b  = blockIdx.y;
    const int p0 = blockIdx.x * PPB;
    const long bp0 = (long)b * P + p0;
    const int tid = threadIdx.x;

    // Position records first (longest dependency chain).
    int4 q[PPB];
    #pragma unroll
    for (int pp = 0; pp < PPB; ++pp) q[pp] = pos[bp0 + pp];

    // Source span for 4 consecutive patches is contiguous: load all of it.
    const f4* __restrict__ src = tok + bp0 * CD4;
    f4 v[PPB * 3];
    #pragma unroll
    for (int j = 0; j < PPB * 3; ++j) v[j] = src[tid + j * BLOCK];

    const long cs_y = (long)W_ * T_ * CD4;   // y+1 cell stride
    const long cs_x = (long)T_ * CD4;        // x+1 cell stride

    #pragma unroll
    for (int pp = 0; pp < PPB; ++pp) {
        const int y = q[pp].x, x = q[pp].y, size = q[pp].z, t = q[pp].w;
        const long base0 = ((((long)b * H_ + y) * W_ + x) * T_ + t) * CD4;

        if (size == 1) {
            f4* __restrict__ dst = out + base0 + tid;
            #pragma unroll
            for (int k = 0; k < 3; ++k)
                __builtin_nontemporal_store(v[pp * 3 + k], dst + k * BLOCK);
        } else {
            f4* __restrict__ d00 = out + base0 + tid;
            f4* __restrict__ d01 = d00 + cs_x;
            f4* __restrict__ d10 = d00 + cs_y;
            f4* __restrict__ d11 = d10 + cs_x;
            #pragma unroll
            for (int k = 0; k < 3; ++k) {
                const f4 w = v[pp * 3 + k];
                __builtin_nontemporal_store(w, d00 + k * BLOCK);
                __builtin_nontemporal_store(w, d01 + k * BLOCK);
                __builtin_nontemporal_store(w, d10 + k * BLOCK);
                __builtin_nontemporal_store(w, d11 + k * BLOCK);
            }
        }
    }
}

extern "C" void kernel_launch(void* const* d_in, const int* in_sizes, int n_in,
                              void* d_out, int out_size, void* d_ws, size_t ws_size,
                              hipStream_t stream) {
    const f4*   tok = (const f4*)d_in[0];    // [B, P*BS, D] f32
    const int4* pos = (const int4*)d_in[1];  // [B, P, 4] i32

    const int Bn = 8;
    const int P  = in_sizes[1] / (Bn * 4);   // 2560

    dim3 grid(P / PPB, Bn);                  // 640 x 8 = 5120 blocks
    apt_scatter_kernel<<<grid, BLOCK, 0, stream>>>(tok, pos, (f4*)d_out, P);
}